// Round 4
// baseline (211.179 us; speedup 1.0000x reference)
//
#include <hip/hip_runtime.h>
#include <hip/hip_bf16.h>

typedef __bf16 bf16x8 __attribute__((ext_vector_type(8)));
typedef float f32x4 __attribute__((ext_vector_type(4)));

#define NPT 50000

// workspace layout (byte offsets; total use = 12,833,796 B)
#define OFF_Y    0u           // bf16 [2][50000][64] = 12,800,000 B (point-major rows)
#define OFF_PRM  12800000u    // f32 [256]: s0, t0, c2, bp
#define OFF_W2   12801024u    // bf16 [64][64] W2'' = w2a * sa[col] * sb[row]
#define OFF_WP   12809216u    // bf16 [64][64] Wp = wf[:, :64] @ w1
#define OFF_W2B  12817408u    // bf16 [64][64] w2b
#define OFF_WN   12825600u    // bf16 [64][64] Wn = wf[:, 64:]
#define OFF_FLAG 12833792u    // int: 1 = device buffers bf16, 0 = f32

__global__ __launch_bounds__(256) void precompute_kernel(
    const void* bn0_g, const void* bn0_b, const void* bn0_m, const void* bn0_v,
    const void* w1, const void* b1,
    const void* bn2a_g, const void* bn2a_b, const void* bn2a_m, const void* bn2a_v,
    const void* w2a,
    const void* bn2b_g, const void* bn2b_b, const void* bn2b_m, const void* bn2b_v,
    const void* w2b, const void* wf, const void* bfv,
    float* __restrict__ prm, __bf16* __restrict__ W2bf, __bf16* __restrict__ Wpbf,
    __bf16* __restrict__ W2Bbf, __bf16* __restrict__ Wnbf, int* __restrict__ flagp)
{
    __shared__ __bf16 w1s[4096];    // 8 KB
    __shared__ __bf16 wfs[8192];    // 16 KB
    __shared__ __bf16 w2as[4096];   // 8 KB
    __shared__ float b1s[64], bfs[64], s2a[64], t2a[64], s2b[64], t2b[64];
    __shared__ int sflag;
    int t = threadIdx.x;

    // dtype detection: bn0_v ~ U(0.5,1.5). If bf16: all 64 bf16 words in range.
    // If f32: only high halves (~32) in range; low halves are mantissa noise.
    if (t == 0) {
        const unsigned short* u = (const unsigned short*)bn0_v;
        int cnt = 0;
        for (int i = 0; i < 64; ++i) {
            float f = __uint_as_float(((unsigned int)u[i]) << 16);
            if (f > 0.4f && f < 1.6f) cnt++;
        }
        int fv = (cnt >= 60) ? 1 : 0;
        sflag = fv;
        *flagp = fv;
    }
    __syncthreads();
    int fl = sflag;

    if (fl) {
        const __bf16* W1  = (const __bf16*)w1;
        const __bf16* W2A = (const __bf16*)w2a;
        const __bf16* WF  = (const __bf16*)wf;
        const __bf16* W2B = (const __bf16*)w2b;
        for (int i = t; i < 4096; i += 256) { w1s[i] = W1[i]; w2as[i] = W2A[i]; W2Bbf[i] = W2B[i]; }
        for (int i = t; i < 8192; i += 256) wfs[i] = WF[i];
        if (t < 64) {
            float s0 = (float)((const __bf16*)bn0_g)[t] / sqrtf((float)((const __bf16*)bn0_v)[t] + 1e-5f);
            prm[t] = s0;
            prm[64 + t] = (float)((const __bf16*)bn0_b)[t] - (float)((const __bf16*)bn0_m)[t] * s0;
            float sa = (float)((const __bf16*)bn2a_g)[t] / sqrtf((float)((const __bf16*)bn2a_v)[t] + 1e-5f);
            s2a[t] = sa;
            t2a[t] = (float)((const __bf16*)bn2a_b)[t] - (float)((const __bf16*)bn2a_m)[t] * sa;
            float sb = (float)((const __bf16*)bn2b_g)[t] / sqrtf((float)((const __bf16*)bn2b_v)[t] + 1e-5f);
            s2b[t] = sb;
            t2b[t] = (float)((const __bf16*)bn2b_b)[t] - (float)((const __bf16*)bn2b_m)[t] * sb;
            b1s[t] = (float)((const __bf16*)b1)[t];
            bfs[t] = (float)((const __bf16*)bfv)[t];
        }
    } else {
        const float* W1  = (const float*)w1;
        const float* W2A = (const float*)w2a;
        const float* WF  = (const float*)wf;
        const float* W2B = (const float*)w2b;
        for (int i = t; i < 4096; i += 256) { w1s[i] = (__bf16)W1[i]; w2as[i] = (__bf16)W2A[i]; W2Bbf[i] = (__bf16)W2B[i]; }
        for (int i = t; i < 8192; i += 256) wfs[i] = (__bf16)WF[i];
        if (t < 64) {
            float s0 = ((const float*)bn0_g)[t] / sqrtf(((const float*)bn0_v)[t] + 1e-5f);
            prm[t] = s0;
            prm[64 + t] = ((const float*)bn0_b)[t] - ((const float*)bn0_m)[t] * s0;
            float sa = ((const float*)bn2a_g)[t] / sqrtf(((const float*)bn2a_v)[t] + 1e-5f);
            s2a[t] = sa;
            t2a[t] = ((const float*)bn2a_b)[t] - ((const float*)bn2a_m)[t] * sa;
            float sb = ((const float*)bn2b_g)[t] / sqrtf(((const float*)bn2b_v)[t] + 1e-5f);
            s2b[t] = sb;
            t2b[t] = ((const float*)bn2b_b)[t] - ((const float*)bn2b_m)[t] * sb;
            b1s[t] = ((const float*)b1)[t];
            bfs[t] = ((const float*)bfv)[t];
        }
    }
    __syncthreads();

    for (int e = t; e < 4096; e += 256) {
        int o = e >> 6, c = e & 63;
        W2bf[e] = (__bf16)((float)w2as[e] * s2a[c] * s2b[o]);
        Wnbf[e] = wfs[o * 128 + 64 + c];
        float acc = 0.f;
        for (int m = 0; m < 64; ++m)
            acc += (float)wfs[o * 128 + m] * (float)w1s[m * 64 + c];
        Wpbf[e] = (__bf16)acc;
    }
    if (t < 64) {
        float acc = 0.f, accb = 0.f;
        for (int c = 0; c < 64; ++c) {
            acc  += (float)w2as[t * 64 + c] * t2a[c];
            accb += (float)wfs[t * 128 + c] * b1s[c];
        }
        prm[128 + t] = s2b[t] * acc + t2b[t];   // c2
        prm[192 + t] = accb + bfs[t];           // bp
    }
}

// pass1: xn = bn0(x); Y = W2''@xn, stored bf16 point-major [b][n][64]
__global__ __launch_bounds__(256) void pass1_kernel(
    const void* x, const float* __restrict__ prm,
    const __bf16* __restrict__ W2bf, __bf16* __restrict__ Y,
    const int* __restrict__ flagp)
{
    __shared__ float xs[64][65];
    int bid = blockIdx.x;
    int b = bid / 782;
    int n0 = (bid % 782) * 64;
    int npts = NPT - n0; if (npts > 64) npts = 64;
    int fl = *flagp;

    if (fl) {
        const __bf16* xb = (const __bf16*)x + (size_t)b * 64 * NPT;
        for (int i = threadIdx.x; i < 4096; i += 256) {
            int c = i >> 6, p = i & 63;
            float v = (p < npts) ? (float)xb[(size_t)c * NPT + n0 + p] : 0.f;
            xs[p][c] = fmaf(v, prm[c], prm[64 + c]);
        }
    } else {
        const float* xb = (const float*)x + (size_t)b * 64 * NPT;
        for (int i = threadIdx.x; i < 4096; i += 256) {
            int c = i >> 6, p = i & 63;
            float v = (p < npts) ? xb[(size_t)c * NPT + n0 + p] : 0.f;
            xs[p][c] = fmaf(v, prm[c], prm[64 + c]);
        }
    }
    __syncthreads();

    int wid = threadIdx.x >> 6, lane = threadIdx.x & 63;
    int pl = (wid << 4) + (lane & 15);       // A-frag m = point
    int hq = lane >> 4;
    int c0 = hq << 3;                        // k-group base

    bf16x8 a0, a1;
    #pragma unroll
    for (int i = 0; i < 8; ++i) {
        a0[i] = (__bf16)xs[pl][c0 + i];
        a1[i] = (__bf16)xs[pl][c0 + 32 + i];
    }

    int ob = lane & 15;                      // B-frag n = output channel
    f32x4 accY[4];
    #pragma unroll
    for (int nt = 0; nt < 4; ++nt) {
        bf16x8 w20 = *(const bf16x8*)(W2bf + (ob + 16 * nt) * 64 + c0);
        bf16x8 w21 = *(const bf16x8*)(W2bf + (ob + 16 * nt) * 64 + c0 + 32);
        f32x4 z = {0.f, 0.f, 0.f, 0.f};
        accY[nt] = __builtin_amdgcn_mfma_f32_16x16x32_bf16(a0, w20, z, 0, 0, 0);
        accY[nt] = __builtin_amdgcn_mfma_f32_16x16x32_bf16(a1, w21, accY[nt], 0, 0, 0);
    }

    // D: col = lane&15 (=o), row = hq*4 + i (=point within 16-tile)
    #pragma unroll
    for (int nt = 0; nt < 4; ++nt) {
        #pragma unroll
        for (int i = 0; i < 4; ++i) {
            int prow = (wid << 4) + (hq << 2) + i;
            if (prow < npts)
                Y[((size_t)b * NPT + n0 + prow) * 64 + ob + 16 * nt] = (__bf16)accY[nt][i];
        }
    }
}

// pass2: out = Wn @ (max_k w2b@relu(Y_j - Y_n + c2)) + Wp@xn + bp
__global__ __launch_bounds__(256) void pass2_kernel(
    const int* __restrict__ nbr, const __bf16* __restrict__ Y,
    const void* x, const float* __restrict__ prm,
    const __bf16* __restrict__ W2Bbf, const __bf16* __restrict__ Wnbf,
    const __bf16* __restrict__ Wpbf, void* out, const int* __restrict__ flagp)
{
    __shared__ float ns[4][16][68];   // per-wave neigh transpose [point][o]
    int wid = threadIdx.x >> 6, lane = threadIdx.x & 63;
    int gtile = blockIdx.x * 4 + wid;
    if (gtile >= 6250) return;
    int b = gtile / 3125;
    int n0 = (gtile % 3125) << 4;
    int fl = *flagp;

    int mo = lane & 15;              // A m-index / B n-index / D col
    int hq = lane >> 4;
    int c0 = hq << 3;                // k-group base
    int nglob = n0 + mo;

    bf16x8 wA[4][2];
    #pragma unroll
    for (int mt = 0; mt < 4; ++mt) {
        wA[mt][0] = *(const bf16x8*)(W2Bbf + (mo + 16 * mt) * 64 + c0);
        wA[mt][1] = *(const bf16x8*)(W2Bbf + (mo + 16 * mt) * 64 + c0 + 32);
    }

    const __bf16* yrow = Y + ((size_t)b * NPT + nglob) * 64;
    float mv[2][8];
    #pragma unroll
    for (int ks = 0; ks < 2; ++ks) {
        bf16x8 yn = *(const bf16x8*)(yrow + c0 + 32 * ks);
        #pragma unroll
        for (int i = 0; i < 8; ++i)
            mv[ks][i] = prm[128 + c0 + 32 * ks + i] - (float)yn[i];
    }

    f32x4 vmax[4];
    #pragma unroll
    for (int mt = 0; mt < 4; ++mt) vmax[mt] = {-3.0e38f, -3.0e38f, -3.0e38f, -3.0e38f};

    const int* nb_base = nbr + (size_t)b * 16 * NPT + NPT + nglob;  // k=1 row
    #pragma unroll
    for (int k = 0; k < 15; ++k) {
        int j = nb_base[(size_t)k * NPT];
        const __bf16* yj = Y + ((size_t)b * NPT + j) * 64;
        bf16x8 y0 = *(const bf16x8*)(yj + c0);
        bf16x8 y1 = *(const bf16x8*)(yj + c0 + 32);
        bf16x8 t0, t1;
        #pragma unroll
        for (int i = 0; i < 8; ++i) {
            t0[i] = (__bf16)fmaxf((float)y0[i] + mv[0][i], 0.f);
            t1[i] = (__bf16)fmaxf((float)y1[i] + mv[1][i], 0.f);
        }
        #pragma unroll
        for (int mt = 0; mt < 4; ++mt) {
            f32x4 h = {0.f, 0.f, 0.f, 0.f};
            h = __builtin_amdgcn_mfma_f32_16x16x32_bf16(wA[mt][0], t0, h, 0, 0, 0);
            h = __builtin_amdgcn_mfma_f32_16x16x32_bf16(wA[mt][1], t1, h, 0, 0, 0);
            #pragma unroll
            for (int i = 0; i < 4; ++i) vmax[mt][i] = fmaxf(vmax[mt][i], h[i]);
        }
    }

    // neigh transpose: D layout -> B-frag layout (per-wave LDS, in-wave ordered)
    #pragma unroll
    for (int mt = 0; mt < 4; ++mt)
        #pragma unroll
        for (int i = 0; i < 4; ++i)
            ns[wid][mo][16 * mt + (hq << 2) + i] = vmax[mt][i];

    bf16x8 nb2[2];
    #pragma unroll
    for (int ks = 0; ks < 2; ++ks)
        #pragma unroll
        for (int i = 0; i < 8; ++i)
            nb2[ks][i] = (__bf16)ns[wid][mo][c0 + 32 * ks + i];

    __builtin_amdgcn_sched_barrier(0);   // keep the tail loads out of the k-loop

    // xn B-frag for the point branch: xn[c][nglob] from x (strided, L2/L3-hot)
    bf16x8 xnb[2];
    if (fl) {
        const __bf16* xp = (const __bf16*)x;
        #pragma unroll
        for (int ks = 0; ks < 2; ++ks)
            #pragma unroll
            for (int i = 0; i < 8; ++i) {
                int c = c0 + 32 * ks + i;
                float v = (float)xp[((size_t)b * 64 + c) * NPT + nglob];
                xnb[ks][i] = (__bf16)fmaf(v, prm[c], prm[64 + c]);
            }
    } else {
        const float* xp = (const float*)x;
        #pragma unroll
        for (int ks = 0; ks < 2; ++ks)
            #pragma unroll
            for (int i = 0; i < 8; ++i) {
                int c = c0 + 32 * ks + i;
                float v = xp[((size_t)b * 64 + c) * NPT + nglob];
                xnb[ks][i] = (__bf16)fmaf(v, prm[c], prm[64 + c]);
            }
    }

    bf16x8 wN[4][2], wP[4][2];
    #pragma unroll
    for (int mt = 0; mt < 4; ++mt) {
        wN[mt][0] = *(const bf16x8*)(Wnbf + (mo + 16 * mt) * 64 + c0);
        wN[mt][1] = *(const bf16x8*)(Wnbf + (mo + 16 * mt) * 64 + c0 + 32);
        wP[mt][0] = *(const bf16x8*)(Wpbf + (mo + 16 * mt) * 64 + c0);
        wP[mt][1] = *(const bf16x8*)(Wpbf + (mo + 16 * mt) * 64 + c0 + 32);
    }

    f32x4 oacc[4];
    #pragma unroll
    for (int mt = 0; mt < 4; ++mt) {
        f32x4 acc = *(const f32x4*)(prm + 192 + 16 * mt + 4 * hq);   // bp[o]
        acc = __builtin_amdgcn_mfma_f32_16x16x32_bf16(wP[mt][0], xnb[0], acc, 0, 0, 0);
        acc = __builtin_amdgcn_mfma_f32_16x16x32_bf16(wP[mt][1], xnb[1], acc, 0, 0, 0);
        acc = __builtin_amdgcn_mfma_f32_16x16x32_bf16(wN[mt][0], nb2[0], acc, 0, 0, 0);
        acc = __builtin_amdgcn_mfma_f32_16x16x32_bf16(wN[mt][1], nb2[1], acc, 0, 0, 0);
        oacc[mt] = acc;
    }

    if (fl) {
        __bf16* ob = (__bf16*)out + (size_t)b * 64 * NPT + n0 + mo;
        #pragma unroll
        for (int mt = 0; mt < 4; ++mt)
            #pragma unroll
            for (int i = 0; i < 4; ++i)
                ob[(size_t)(16 * mt + (hq << 2) + i) * NPT] = (__bf16)oacc[mt][i];
    } else {
        float* ob = (float*)out + (size_t)b * 64 * NPT + n0 + mo;
        #pragma unroll
        for (int mt = 0; mt < 4; ++mt)
            #pragma unroll
            for (int i = 0; i < 4; ++i)
                ob[(size_t)(16 * mt + (hq << 2) + i) * NPT] = oacc[mt][i];
    }
}

extern "C" void kernel_launch(void* const* d_in, const int* in_sizes, int n_in,
                              void* d_out, int out_size, void* d_ws, size_t ws_size,
                              hipStream_t stream) {
    const void* x      = d_in[0];
    const int*  nbr    = (const int*)d_in[1];

    char* ws = (char*)d_ws;
    __bf16* Y     = (__bf16*)(ws + OFF_Y);
    float*  prm   = (float*)(ws + OFF_PRM);
    __bf16* W2bf  = (__bf16*)(ws + OFF_W2);
    __bf16* Wpbf  = (__bf16*)(ws + OFF_WP);
    __bf16* W2Bbf = (__bf16*)(ws + OFF_W2B);
    __bf16* Wnbf  = (__bf16*)(ws + OFF_WN);
    int*    flagp = (int*)(ws + OFF_FLAG);

    precompute_kernel<<<1, 256, 0, stream>>>(
        d_in[2], d_in[3], d_in[4], d_in[5], d_in[6], d_in[7],
        d_in[8], d_in[9], d_in[10], d_in[11], d_in[12],
        d_in[13], d_in[14], d_in[15], d_in[16], d_in[17], d_in[18], d_in[19],
        prm, W2bf, Wpbf, W2Bbf, Wnbf, flagp);

    pass1_kernel<<<1564, 256, 0, stream>>>(x, prm, W2bf, Y, flagp);

    pass2_kernel<<<1563, 256, 0, stream>>>(nbr, Y, x, prm, W2Bbf, Wnbf, Wpbf, d_out, flagp);
}

// Round 5
// 199.538 us; speedup vs baseline: 1.0583x; 1.0583x over previous
//
#include <hip/hip_runtime.h>
#include <hip/hip_bf16.h>

typedef __bf16 bf16x8 __attribute__((ext_vector_type(8)));
typedef float f32x4 __attribute__((ext_vector_type(4)));

#define NPT 50000

// workspace layout (byte offsets; total use = 12,833,796 B)
#define OFF_Y    0u           // bf16 [2][50000][64] = 12,800,000 B (point-major rows)
#define OFF_PRM  12800000u    // f32 [256]: s0, t0, c2, bp
#define OFF_W2   12801024u    // bf16 [64][64] W2'' = w2a * sa[col] * sb[row]
#define OFF_WP   12809216u    // bf16 [64][64] Wp = wf[:, :64] @ w1
#define OFF_W2B  12817408u    // bf16 [64][64] w2b
#define OFF_WN   12825600u    // bf16 [64][64] Wn = wf[:, 64:]
#define OFF_FLAG 12833792u    // int: 1 = device buffers bf16, 0 = f32

__global__ __launch_bounds__(256) void precompute_kernel(
    const void* bn0_g, const void* bn0_b, const void* bn0_m, const void* bn0_v,
    const void* w1, const void* b1,
    const void* bn2a_g, const void* bn2a_b, const void* bn2a_m, const void* bn2a_v,
    const void* w2a,
    const void* bn2b_g, const void* bn2b_b, const void* bn2b_m, const void* bn2b_v,
    const void* w2b, const void* wf, const void* bfv,
    float* __restrict__ prm, __bf16* __restrict__ W2bf, __bf16* __restrict__ Wpbf,
    __bf16* __restrict__ W2Bbf, __bf16* __restrict__ Wnbf, int* __restrict__ flagp)
{
    __shared__ __bf16 w1s[4096];    // 8 KB
    __shared__ __bf16 wfs[8192];    // 16 KB
    __shared__ __bf16 w2as[4096];   // 8 KB
    __shared__ float b1s[64], bfs[64], s2a[64], t2a[64], s2b[64], t2b[64];
    __shared__ int sflag;
    int t = threadIdx.x;

    // dtype detection: bn0_v ~ U(0.5,1.5). If bf16: all 64 bf16 words in range.
    // If f32: only high halves (~32) in range; low halves are mantissa noise.
    if (t == 0) {
        const unsigned short* u = (const unsigned short*)bn0_v;
        int cnt = 0;
        for (int i = 0; i < 64; ++i) {
            float f = __uint_as_float(((unsigned int)u[i]) << 16);
            if (f > 0.4f && f < 1.6f) cnt++;
        }
        int fv = (cnt >= 60) ? 1 : 0;
        sflag = fv;
        *flagp = fv;
    }
    __syncthreads();
    int fl = sflag;

    if (fl) {
        const __bf16* W1  = (const __bf16*)w1;
        const __bf16* W2A = (const __bf16*)w2a;
        const __bf16* WF  = (const __bf16*)wf;
        const __bf16* W2B = (const __bf16*)w2b;
        for (int i = t; i < 4096; i += 256) { w1s[i] = W1[i]; w2as[i] = W2A[i]; W2Bbf[i] = W2B[i]; }
        for (int i = t; i < 8192; i += 256) wfs[i] = WF[i];
        if (t < 64) {
            float s0 = (float)((const __bf16*)bn0_g)[t] / sqrtf((float)((const __bf16*)bn0_v)[t] + 1e-5f);
            prm[t] = s0;
            prm[64 + t] = (float)((const __bf16*)bn0_b)[t] - (float)((const __bf16*)bn0_m)[t] * s0;
            float sa = (float)((const __bf16*)bn2a_g)[t] / sqrtf((float)((const __bf16*)bn2a_v)[t] + 1e-5f);
            s2a[t] = sa;
            t2a[t] = (float)((const __bf16*)bn2a_b)[t] - (float)((const __bf16*)bn2a_m)[t] * sa;
            float sb = (float)((const __bf16*)bn2b_g)[t] / sqrtf((float)((const __bf16*)bn2b_v)[t] + 1e-5f);
            s2b[t] = sb;
            t2b[t] = (float)((const __bf16*)bn2b_b)[t] - (float)((const __bf16*)bn2b_m)[t] * sb;
            b1s[t] = (float)((const __bf16*)b1)[t];
            bfs[t] = (float)((const __bf16*)bfv)[t];
        }
    } else {
        const float* W1  = (const float*)w1;
        const float* W2A = (const float*)w2a;
        const float* WF  = (const float*)wf;
        const float* W2B = (const float*)w2b;
        for (int i = t; i < 4096; i += 256) { w1s[i] = (__bf16)W1[i]; w2as[i] = (__bf16)W2A[i]; W2Bbf[i] = (__bf16)W2B[i]; }
        for (int i = t; i < 8192; i += 256) wfs[i] = (__bf16)WF[i];
        if (t < 64) {
            float s0 = ((const float*)bn0_g)[t] / sqrtf(((const float*)bn0_v)[t] + 1e-5f);
            prm[t] = s0;
            prm[64 + t] = ((const float*)bn0_b)[t] - ((const float*)bn0_m)[t] * s0;
            float sa = ((const float*)bn2a_g)[t] / sqrtf(((const float*)bn2a_v)[t] + 1e-5f);
            s2a[t] = sa;
            t2a[t] = ((const float*)bn2a_b)[t] - ((const float*)bn2a_m)[t] * sa;
            float sb = ((const float*)bn2b_g)[t] / sqrtf(((const float*)bn2b_v)[t] + 1e-5f);
            s2b[t] = sb;
            t2b[t] = ((const float*)bn2b_b)[t] - ((const float*)bn2b_m)[t] * sb;
            b1s[t] = ((const float*)b1)[t];
            bfs[t] = ((const float*)bfv)[t];
        }
    }
    __syncthreads();

    for (int e = t; e < 4096; e += 256) {
        int o = e >> 6, c = e & 63;
        W2bf[e] = (__bf16)((float)w2as[e] * s2a[c] * s2b[o]);
        Wnbf[e] = wfs[o * 128 + 64 + c];
        float acc = 0.f;
        for (int m = 0; m < 64; ++m)
            acc += (float)wfs[o * 128 + m] * (float)w1s[m * 64 + c];
        Wpbf[e] = (__bf16)acc;
    }
    if (t < 64) {
        float acc = 0.f, accb = 0.f;
        for (int c = 0; c < 64; ++c) {
            acc  += (float)w2as[t * 64 + c] * t2a[c];
            accb += (float)wfs[t * 128 + c] * b1s[c];
        }
        prm[128 + t] = s2b[t] * acc + t2b[t];   // c2
        prm[192 + t] = accb + bfs[t];           // bp
    }
}

// pass1: xn = bn0(x); Y = W2''@xn, stored bf16 point-major [b][n][64]
__global__ __launch_bounds__(256) void pass1_kernel(
    const void* x, const float* __restrict__ prm,
    const __bf16* __restrict__ W2bf, __bf16* __restrict__ Y,
    const int* __restrict__ flagp)
{
    __shared__ float xs[64][65];
    int bid = blockIdx.x;
    int b = bid / 782;
    int n0 = (bid % 782) * 64;
    int npts = NPT - n0; if (npts > 64) npts = 64;
    int fl = *flagp;

    if (fl) {
        const __bf16* xb = (const __bf16*)x + (size_t)b * 64 * NPT;
        for (int i = threadIdx.x; i < 4096; i += 256) {
            int c = i >> 6, p = i & 63;
            float v = (p < npts) ? (float)xb[(size_t)c * NPT + n0 + p] : 0.f;
            xs[p][c] = fmaf(v, prm[c], prm[64 + c]);
        }
    } else {
        const float* xb = (const float*)x + (size_t)b * 64 * NPT;
        for (int i = threadIdx.x; i < 4096; i += 256) {
            int c = i >> 6, p = i & 63;
            float v = (p < npts) ? xb[(size_t)c * NPT + n0 + p] : 0.f;
            xs[p][c] = fmaf(v, prm[c], prm[64 + c]);
        }
    }
    __syncthreads();

    int wid = threadIdx.x >> 6, lane = threadIdx.x & 63;
    int pl = (wid << 4) + (lane & 15);       // A-frag m = point
    int hq = lane >> 4;
    int c0 = hq << 3;                        // k-group base

    bf16x8 a0, a1;
    #pragma unroll
    for (int i = 0; i < 8; ++i) {
        a0[i] = (__bf16)xs[pl][c0 + i];
        a1[i] = (__bf16)xs[pl][c0 + 32 + i];
    }

    int ob = lane & 15;                      // B-frag n = output channel
    f32x4 accY[4];
    #pragma unroll
    for (int nt = 0; nt < 4; ++nt) {
        bf16x8 w20 = *(const bf16x8*)(W2bf + (ob + 16 * nt) * 64 + c0);
        bf16x8 w21 = *(const bf16x8*)(W2bf + (ob + 16 * nt) * 64 + c0 + 32);
        f32x4 z = {0.f, 0.f, 0.f, 0.f};
        accY[nt] = __builtin_amdgcn_mfma_f32_16x16x32_bf16(a0, w20, z, 0, 0, 0);
        accY[nt] = __builtin_amdgcn_mfma_f32_16x16x32_bf16(a1, w21, accY[nt], 0, 0, 0);
    }

    // D: col = lane&15 (=o), row = hq*4 + i (=point within 16-tile)
    #pragma unroll
    for (int nt = 0; nt < 4; ++nt) {
        #pragma unroll
        for (int i = 0; i < 4; ++i) {
            int prow = (wid << 4) + (hq << 2) + i;
            if (prow < npts)
                Y[((size_t)b * NPT + n0 + prow) * 64 + ob + 16 * nt] = (__bf16)accY[nt][i];
        }
    }
}

// pass2: out = Wn @ (max_k w2b@relu(Y_j - Y_n + c2)) + Wp@xn + bp
// 2 waves per 16-point tile; wave h handles neighbors k in [7h, 7h+7]
// (k=7 done by both — idempotent under max). vmax combined via LDS.
__global__ __launch_bounds__(256) void pass2_kernel(
    const int* __restrict__ nbr, const __bf16* __restrict__ Y,
    const void* x, const float* __restrict__ prm,
    const __bf16* __restrict__ W2Bbf, const __bf16* __restrict__ Wnbf,
    const __bf16* __restrict__ Wpbf, void* out, const int* __restrict__ flagp)
{
    __shared__ float ns[2][2][16][69];   // [tile][half][point(mo)][ch], pad 69 -> conflict-free
    int wid = threadIdx.x >> 6, lane = threadIdx.x & 63;
    int tile = wid >> 1, h = wid & 1;
    int gtile = blockIdx.x * 2 + tile;   // grid 3125 x 2 tiles = 6250 exactly
    int b = gtile / 3125;
    int n0 = (gtile % 3125) << 4;
    int fl = *flagp;

    int mo = lane & 15;              // A m-index / B n-index / D col
    int hq = lane >> 4;
    int c0 = hq << 3;                // k-group base
    int nglob = n0 + mo;

    bf16x8 wA[4][2];
    #pragma unroll
    for (int mt = 0; mt < 4; ++mt) {
        wA[mt][0] = *(const bf16x8*)(W2Bbf + (mo + 16 * mt) * 64 + c0);
        wA[mt][1] = *(const bf16x8*)(W2Bbf + (mo + 16 * mt) * 64 + c0 + 32);
    }

    const __bf16* yrow = Y + ((size_t)b * NPT + nglob) * 64;
    float mv[2][8];
    #pragma unroll
    for (int ks = 0; ks < 2; ++ks) {
        bf16x8 yn = *(const bf16x8*)(yrow + c0 + 32 * ks);
        #pragma unroll
        for (int i = 0; i < 8; ++i)
            mv[ks][i] = prm[128 + c0 + 32 * ks + i] - (float)yn[i];
    }

    // ---- gather phase: 8 neighbors, all idx + row loads issued up front ----
    const int* nb_base = nbr + (size_t)b * 16 * NPT + NPT + nglob;  // k=1 row
    int kbase = h * 7;
    int j[8];
    #pragma unroll
    for (int kk = 0; kk < 8; ++kk)
        j[kk] = nb_base[(size_t)(kbase + kk) * NPT];

    bf16x8 y0v[8], y1v[8];
    #pragma unroll
    for (int kk = 0; kk < 8; ++kk) {
        const __bf16* yj = Y + ((size_t)b * NPT + j[kk]) * 64;
        y0v[kk] = *(const bf16x8*)(yj + c0);
        y1v[kk] = *(const bf16x8*)(yj + c0 + 32);
    }

    f32x4 vmax[4];
    #pragma unroll
    for (int mt = 0; mt < 4; ++mt) vmax[mt] = {-3.0e38f, -3.0e38f, -3.0e38f, -3.0e38f};

    #pragma unroll
    for (int kk = 0; kk < 8; ++kk) {
        bf16x8 t0, t1;
        #pragma unroll
        for (int i = 0; i < 8; ++i) {
            t0[i] = (__bf16)fmaxf((float)y0v[kk][i] + mv[0][i], 0.f);
            t1[i] = (__bf16)fmaxf((float)y1v[kk][i] + mv[1][i], 0.f);
        }
        #pragma unroll
        for (int mt = 0; mt < 4; ++mt) {
            f32x4 hh = {0.f, 0.f, 0.f, 0.f};
            hh = __builtin_amdgcn_mfma_f32_16x16x32_bf16(wA[mt][0], t0, hh, 0, 0, 0);
            hh = __builtin_amdgcn_mfma_f32_16x16x32_bf16(wA[mt][1], t1, hh, 0, 0, 0);
            #pragma unroll
            for (int i = 0; i < 4; ++i) vmax[mt][i] = fmaxf(vmax[mt][i], hh[i]);
        }
    }

    // vmax -> LDS (D layout: point=mo, ch = 16mt + 4hq + i)
    #pragma unroll
    for (int mt = 0; mt < 4; ++mt)
        #pragma unroll
        for (int i = 0; i < 4; ++i)
            ns[tile][h][mo][16 * mt + (hq << 2) + i] = vmax[mt][i];

    __syncthreads();

    // combine halves, build B-frag for finish GEMM
    bf16x8 nb2[2];
    #pragma unroll
    for (int ks = 0; ks < 2; ++ks)
        #pragma unroll
        for (int i = 0; i < 8; ++i) {
            int c = c0 + 32 * ks + i;
            nb2[ks][i] = (__bf16)fmaxf(ns[tile][0][mo][c], ns[tile][1][mo][c]);
        }

    __builtin_amdgcn_sched_barrier(0);   // keep tail loads out of the gather loop

    // xn B-frag for the point branch: xn[c][nglob] from x (L2/L3-hot)
    bf16x8 xnb[2];
    if (fl) {
        const __bf16* xp = (const __bf16*)x;
        #pragma unroll
        for (int ks = 0; ks < 2; ++ks)
            #pragma unroll
            for (int i = 0; i < 8; ++i) {
                int c = c0 + 32 * ks + i;
                float v = (float)xp[((size_t)b * 64 + c) * NPT + nglob];
                xnb[ks][i] = (__bf16)fmaf(v, prm[c], prm[64 + c]);
            }
    } else {
        const float* xp = (const float*)x;
        #pragma unroll
        for (int ks = 0; ks < 2; ++ks)
            #pragma unroll
            for (int i = 0; i < 8; ++i) {
                int c = c0 + 32 * ks + i;
                float v = xp[((size_t)b * 64 + c) * NPT + nglob];
                xnb[ks][i] = (__bf16)fmaf(v, prm[c], prm[64 + c]);
            }
    }

    // finish: this wave handles output-channel tiles mt = 2h, 2h+1
    #pragma unroll
    for (int q = 0; q < 2; ++q) {
        int mt = 2 * h + q;
        bf16x8 wn0 = *(const bf16x8*)(Wnbf + (mo + 16 * mt) * 64 + c0);
        bf16x8 wn1 = *(const bf16x8*)(Wnbf + (mo + 16 * mt) * 64 + c0 + 32);
        bf16x8 wp0 = *(const bf16x8*)(Wpbf + (mo + 16 * mt) * 64 + c0);
        bf16x8 wp1 = *(const bf16x8*)(Wpbf + (mo + 16 * mt) * 64 + c0 + 32);
        f32x4 acc = *(const f32x4*)(prm + 192 + 16 * mt + 4 * hq);   // bp[o]
        acc = __builtin_amdgcn_mfma_f32_16x16x32_bf16(wp0, xnb[0], acc, 0, 0, 0);
        acc = __builtin_amdgcn_mfma_f32_16x16x32_bf16(wp1, xnb[1], acc, 0, 0, 0);
        acc = __builtin_amdgcn_mfma_f32_16x16x32_bf16(wn0, nb2[0], acc, 0, 0, 0);
        acc = __builtin_amdgcn_mfma_f32_16x16x32_bf16(wn1, nb2[1], acc, 0, 0, 0);

        if (fl) {
            __bf16* ob = (__bf16*)out + (size_t)b * 64 * NPT + n0 + mo;
            #pragma unroll
            for (int i = 0; i < 4; ++i)
                ob[(size_t)(16 * mt + (hq << 2) + i) * NPT] = (__bf16)acc[i];
        } else {
            float* ob = (float*)out + (size_t)b * 64 * NPT + n0 + mo;
            #pragma unroll
            for (int i = 0; i < 4; ++i)
                ob[(size_t)(16 * mt + (hq << 2) + i) * NPT] = acc[i];
        }
    }
}

extern "C" void kernel_launch(void* const* d_in, const int* in_sizes, int n_in,
                              void* d_out, int out_size, void* d_ws, size_t ws_size,
                              hipStream_t stream) {
    const void* x      = d_in[0];
    const int*  nbr    = (const int*)d_in[1];

    char* ws = (char*)d_ws;
    __bf16* Y     = (__bf16*)(ws + OFF_Y);
    float*  prm   = (float*)(ws + OFF_PRM);
    __bf16* W2bf  = (__bf16*)(ws + OFF_W2);
    __bf16* Wpbf  = (__bf16*)(ws + OFF_WP);
    __bf16* W2Bbf = (__bf16*)(ws + OFF_W2B);
    __bf16* Wnbf  = (__bf16*)(ws + OFF_WN);
    int*    flagp = (int*)(ws + OFF_FLAG);

    precompute_kernel<<<1, 256, 0, stream>>>(
        d_in[2], d_in[3], d_in[4], d_in[5], d_in[6], d_in[7],
        d_in[8], d_in[9], d_in[10], d_in[11], d_in[12],
        d_in[13], d_in[14], d_in[15], d_in[16], d_in[17], d_in[18], d_in[19],
        prm, W2bf, Wpbf, W2Bbf, Wnbf, flagp);

    pass1_kernel<<<1564, 256, 0, stream>>>(x, prm, W2bf, Y, flagp);

    pass2_kernel<<<3125, 256, 0, stream>>>(nbr, Y, x, prm, W2Bbf, Wnbf, Wpbf, d_out, flagp);
}